// Round 3
// baseline (490.015 us; speedup 1.0000x reference)
//
#include <hip/hip_runtime.h>
#include <hip/hip_bf16.h>
#include <math.h>

#define BB 8
#define NN 2048
#define HH 128
#define BN (BB*NN)   // 16384

typedef unsigned short ushort_t;
typedef __attribute__((ext_vector_type(8))) short short8_t;
typedef __attribute__((ext_vector_type(4))) float f32x4_t;

// ---------------------------------------------------------------------------
// workspace layout (bytes)
// ---------------------------------------------------------------------------
#define WS_FLAG   0
#define WS_W1T    4096                      // 128*128*4  = 65536
#define WS_W2T    (WS_W1T + 65536)          // 128*128*4  = 65536
#define WS_WIHT   (WS_W2T + 65536)          // 128*384*4  = 196608
#define WS_WHHT   (WS_WIHT + 196608)        // 128*384*4  = 196608
#define WS_B1     (WS_WHHT + 196608)        // 512
#define WS_B2     (WS_B1 + 512)             // 512
#define WS_BIH    (WS_B2 + 512)             // 1536
#define WS_BHH    (WS_BIH + 1536)           // 1536
#define WS_M      532480                    // mT_hi [8][128][2048] bf16 = 4 MiB
#define WS_MLO    (WS_M + 4194304)          // mT_lo (fp32-split path) = 4 MiB

template<bool BF16>
__device__ __forceinline__ float ldf(const void* p, size_t off) {
    if constexpr (BF16) return (float)((const __bf16*)p)[off];
    else                return ((const float*)p)[off];
}

template<bool BF16>
__device__ __forceinline__ float4 ld4(const void* p, size_t off) {
    if constexpr (BF16) {
        const ushort4 u = *reinterpret_cast<const ushort4*>((const ushort_t*)p + off);
        float4 r;
        r.x = __uint_as_float((unsigned)u.x << 16);
        r.y = __uint_as_float((unsigned)u.y << 16);
        r.z = __uint_as_float((unsigned)u.z << 16);
        r.w = __uint_as_float((unsigned)u.w << 16);
        return r;
    } else {
        return *reinterpret_cast<const float4*>((const float*)p + off);
    }
}

__device__ __forceinline__ float f4c(const float4 v, int i) {
    switch (i) { case 0: return v.x; case 1: return v.y; case 2: return v.z; default: return v.w; }
}

__device__ __forceinline__ ushort_t bf_rn(float v) {   // round-to-nearest bf16 bits
    __bf16 b = (__bf16)v;
    return *(ushort_t*)&b;
}
__device__ __forceinline__ float bf_to_f(ushort_t u) {
    return __uint_as_float((unsigned)u << 16);
}

__device__ __forceinline__ f32x4_t mfma16(short8_t a, short8_t b, f32x4_t c) {
    return __builtin_amdgcn_mfma_f32_16x16x32_bf16(a, b, c, 0, 0, 0);
}

// ---------------------------------------------------------------------------
// detect input dtype from A's bit patterns.
// bf16 U(0,1): every ushort <= 0x3F80.  fp32: ~37% of all ushorts exceed.
// ---------------------------------------------------------------------------
__global__ void detect_kernel(const ushort_t* __restrict__ Au, int* __restrict__ flag)
{
    __shared__ int cnt;
    if (threadIdx.x == 0) cnt = 0;
    __syncthreads();
    int c = 0;
    for (int i = threadIdx.x; i < 4096; i += 256)
        if (Au[i] > 0x3F80u) ++c;
    atomicAdd(&cnt, c);
    __syncthreads();
    if (threadIdx.x == 0) *flag = (cnt < 100) ? 1 : 0;   // 1 = bf16 inputs
}

// ---------------------------------------------------------------------------
// prep: transpose all weights to fp32 W^T[k][c] in ws + widen biases to fp32.
// ---------------------------------------------------------------------------
template<bool BF16>
__global__ __launch_bounds__(256) void prep_kernel(
    const int* __restrict__ flag,
    const void* __restrict__ W1, const void* __restrict__ b1,
    const void* __restrict__ W2, const void* __restrict__ b2,
    const void* __restrict__ Wih, const void* __restrict__ Whh,
    const void* __restrict__ bih, const void* __restrict__ bhh,
    char* __restrict__ ws)
{
    if (*flag != (int)BF16) return;
    float* W1T  = (float*)(ws + WS_W1T);
    float* W2T  = (float*)(ws + WS_W2T);
    float* WihT = (float*)(ws + WS_WIHT);
    float* WhhT = (float*)(ws + WS_WHHT);
    float* b1f  = (float*)(ws + WS_B1);
    float* b2f  = (float*)(ws + WS_B2);
    float* bihf = (float*)(ws + WS_BIH);
    float* bhhf = (float*)(ws + WS_BHH);

    int t = blockIdx.x * 256 + threadIdx.x;
    int nth = gridDim.x * 256;
    for (int i = t; i < HH * HH; i += nth) {
        int k = i >> 7, c = i & 127;
        W1T[i] = ldf<BF16>(W1, (size_t)c * HH + k);
        W2T[i] = ldf<BF16>(W2, (size_t)c * HH + k);
    }
    for (int i = t; i < 3 * HH * HH; i += nth) {
        int k = i / 384, c = i - k * 384;
        WihT[i] = ldf<BF16>(Wih, (size_t)c * HH + k);
        WhhT[i] = ldf<BF16>(Whh, (size_t)c * HH + k);
    }
    if (t < HH)     { b1f[t] = ldf<BF16>(b1, t);  b2f[t] = ldf<BF16>(b2, t); }
    if (t < 3 * HH) { bihf[t] = ldf<BF16>(bih, t); bhhf[t] = ldf<BF16>(bhh, t); }
}

// ---------------------------------------------------------------------------
// MLP: m = relu(relu(h@W1^T+b1)@W2^T+b2), 32 rows/block, 4x4 register tiles.
// Output written TRANSPOSED as bf16: mT[b][c][n].  SPLIT: + lo-residual.
// launch_bounds(256,1): allow full VGPR budget (grid caps occupancy anyway).
// ---------------------------------------------------------------------------
template<bool BF16, bool SPLIT>
__global__ __launch_bounds__(256, 1) void mlp_kernel(
    const int* __restrict__ flag, const void* __restrict__ h,
    char* __restrict__ ws)
{
    if (*flag != (int)BF16) return;
    __shared__ float hrs[32][HH];
    __shared__ float m1[32][132];      // +4 pad: bank spread for transpose read
    const float* W1T = (const float*)(ws + WS_W1T);
    const float* W2T = (const float*)(ws + WS_W2T);
    const float* b1f = (const float*)(ws + WS_B1);
    const float* b2f = (const float*)(ws + WS_B2);
    ushort_t* mTh = (ushort_t*)(ws + WS_M);
    ushort_t* mTl = (ushort_t*)(ws + WS_MLO);

    int tid = threadIdx.x;
    int row0 = blockIdx.x * 32;
    int rg = tid >> 5, cg = tid & 31;
    int r0 = rg * 4, c0 = cg * 4;

#pragma unroll
    for (int j = 0; j < 4; ++j) {
        int e = j * 256 + tid;
        int r = e >> 5, c4 = e & 31;
        *(float4*)&hrs[r][c4 * 4] = ld4<BF16>(h, (size_t)(row0 + r) * HH + c4 * 4);
    }
    __syncthreads();

    // ---- layer 1 ----
    {
        float acc[4][4];
        float4 bv = *(const float4*)(b1f + c0);
#pragma unroll
        for (int r = 0; r < 4; ++r) {
            acc[r][0] = bv.x; acc[r][1] = bv.y; acc[r][2] = bv.z; acc[r][3] = bv.w;
        }
        for (int k = 0; k < HH; k += 4) {
            float4 av[4], wv[4];
#pragma unroll
            for (int r = 0; r < 4; ++r) av[r] = *(const float4*)&hrs[r0 + r][k];
#pragma unroll
            for (int kk = 0; kk < 4; ++kk) wv[kk] = *(const float4*)(W1T + (size_t)(k + kk) * HH + c0);
#pragma unroll
            for (int kk = 0; kk < 4; ++kk) {
                float4 w = wv[kk];
#pragma unroll
                for (int r = 0; r < 4; ++r) {
                    float a = f4c(av[r], kk);
                    acc[r][0] = fmaf(a, w.x, acc[r][0]);
                    acc[r][1] = fmaf(a, w.y, acc[r][1]);
                    acc[r][2] = fmaf(a, w.z, acc[r][2]);
                    acc[r][3] = fmaf(a, w.w, acc[r][3]);
                }
            }
        }
#pragma unroll
        for (int r = 0; r < 4; ++r)
#pragma unroll
            for (int j = 0; j < 4; ++j)
                m1[r0 + r][c0 + j] = fmaxf(acc[r][j], 0.f);
    }
    __syncthreads();

    // ---- layer 2 ----
    {
        float acc[4][4];
        float4 bv = *(const float4*)(b2f + c0);
#pragma unroll
        for (int r = 0; r < 4; ++r) {
            acc[r][0] = bv.x; acc[r][1] = bv.y; acc[r][2] = bv.z; acc[r][3] = bv.w;
        }
        for (int k = 0; k < HH; k += 4) {
            float4 av[4], wv[4];
#pragma unroll
            for (int r = 0; r < 4; ++r) av[r] = *(const float4*)&m1[r0 + r][k];
#pragma unroll
            for (int kk = 0; kk < 4; ++kk) wv[kk] = *(const float4*)(W2T + (size_t)(k + kk) * HH + c0);
#pragma unroll
            for (int kk = 0; kk < 4; ++kk) {
                float4 w = wv[kk];
#pragma unroll
                for (int r = 0; r < 4; ++r) {
                    float a = f4c(av[r], kk);
                    acc[r][0] = fmaf(a, w.x, acc[r][0]);
                    acc[r][1] = fmaf(a, w.y, acc[r][1]);
                    acc[r][2] = fmaf(a, w.z, acc[r][2]);
                    acc[r][3] = fmaf(a, w.w, acc[r][3]);
                }
            }
        }
        __syncthreads();   // all m1 reads done before overwrite
#pragma unroll
        for (int r = 0; r < 4; ++r)
#pragma unroll
            for (int j = 0; j < 4; ++j)
                m1[r0 + r][c0 + j] = fmaxf(acc[r][j], 0.f);
    }
    __syncthreads();

    // ---- export transposed: mT[b][c][n], coalesced 64B segments ----
    {
        int rr = tid & 31, cq = tid >> 5;
        int bb = row0 >> 11, nloc = row0 & 2047;
#pragma unroll
        for (int p = 0; p < 16; ++p) {
            int c = p * 8 + cq;
            float v = m1[rr][c];
            ushort_t hb = bf_rn(v);
            size_t o = (size_t)(bb * 128 + c) * NN + nloc + rr;
            mTh[o] = hb;
            if constexpr (SPLIT)
                mTl[o] = bf_rn(v - bf_to_f(hb));
        }
    }
}

// ---------------------------------------------------------------------------
// fused: phase 1 msg = relu(A@m) via MFMA 16x16x32 bf16, LDS-free.
// B-frag loads hoisted into arrays (>=10 loads in flight before first wait).
// Phase 2: scalar GRU gates, k-loop unrolled x2 for prefetch distance.
// launch_bounds(256,1): phase 2 needs ~190 live VGPRs; at (256,2) the
// compiler allocated 64 and spilled the gate accumulators to scratch every
// k-iter -> the 263us plateau.  Occupancy is grid-capped at 2 blocks/CU
// regardless, so the extra registers are free.
// ---------------------------------------------------------------------------
template<bool BF16, bool SPLIT>
__global__ __launch_bounds__(256, 1) void fused_kernel(
    const int* __restrict__ flag, const void* __restrict__ A,
    const void* __restrict__ h, const char* __restrict__ ws,
    void* __restrict__ out)
{
    if (*flag != (int)BF16) return;
    __shared__ float hrs[32][HH];
    __shared__ float msgs[32][132];    // +4 pad

    const float* WihT = (const float*)(ws + WS_WIHT);
    const float* WhhT = (const float*)(ws + WS_WHHT);
    const float* bihf = (const float*)(ws + WS_BIH);
    const float* bhhf = (const float*)(ws + WS_BHH);
    const ushort_t* mTh = (const ushort_t*)(ws + WS_M);
    const ushort_t* mTl = (const ushort_t*)(ws + WS_MLO);

    int tid = threadIdx.x;
    int b = blockIdx.x & 7, rt = blockIdx.x >> 3;
    int n0 = rt * 32;
    int rg = tid >> 5, cg = tid & 31;
    int r0 = rg * 4, c0 = cg * 4;

    // stage h rows (consumed in phase 2 after the barrier)
#pragma unroll
    for (int j = 0; j < 4; ++j) {
        int e = j * 256 + tid;
        int r = e >> 5, c4 = e & 31;
        *(float4*)&hrs[r][c4 * 4] = ld4<BF16>(h, ((size_t)(b * NN + n0 + r)) * HH + c4 * 4);
    }

    // ---- phase 1: MFMA ----
    const int lane = tid & 63, wv = tid >> 6;
    const int lr = lane & 15, hq = lane >> 4;        // frag row/col & k-half
    const int wr = (wv & 1) * 16, wc = (wv >> 1) * 64;

    f32x4_t acc[4];
#pragma unroll
    for (int t = 0; t < 4; ++t) { acc[t][0] = 0.f; acc[t][1] = 0.f; acc[t][2] = 0.f; acc[t][3] = 0.f; }

    const size_t abase = ((size_t)(b * NN + n0 + wr + lr)) * NN + 8 * hq;   // A[row][k]
    const size_t mbase = ((size_t)(b * 128 + wc + lr)) * NN + 8 * hq;       // mT[col][k]

#pragma unroll 2
    for (int k0 = 0; k0 < NN; k0 += 32) {
        // hoist ALL loads of this iteration first: A (1-2 vec loads) + 4 bh
        // (+4 bl) are independent -> issue together, wait once.
        short8_t bh[4], bl[4];
#pragma unroll
        for (int t = 0; t < 4; ++t)
            bh[t] = *reinterpret_cast<const short8_t*>(mTh + mbase + (size_t)t * 16 * NN + k0);
        if constexpr (!BF16 && SPLIT) {
#pragma unroll
            for (int t = 0; t < 4; ++t)
                bl[t] = *reinterpret_cast<const short8_t*>(mTl + mbase + (size_t)t * 16 * NN + k0);
        }

        short8_t ah, al;
        if constexpr (BF16) {
            ah = *reinterpret_cast<const short8_t*>((const ushort_t*)A + abase + k0);
        } else {
            const float* ap = (const float*)A + abase + k0;
            float4 a0 = *reinterpret_cast<const float4*>(ap);
            float4 a1 = *reinterpret_cast<const float4*>(ap + 4);
#pragma unroll
            for (int j = 0; j < 4; ++j) {
                float f0 = f4c(a0, j), f1 = f4c(a1, j);
                ushort_t h0 = bf_rn(f0), h1 = bf_rn(f1);
                ah[j]     = (short)h0;
                ah[j + 4] = (short)h1;
                al[j]     = (short)bf_rn(f0 - bf_to_f(h0));
                al[j + 4] = (short)bf_rn(f1 - bf_to_f(h1));
            }
        }
#pragma unroll
        for (int t = 0; t < 4; ++t) {
            acc[t] = mfma16(ah, bh[t], acc[t]);
            if constexpr (!BF16) {
                acc[t] = mfma16(al, bh[t], acc[t]);      // A_lo * m_hi
                if constexpr (SPLIT)
                    acc[t] = mfma16(ah, bl[t], acc[t]);  // A_hi * m_lo
            }
        }
    }

    // C/D layout (m89-verified): col = lane&15, row = (lane>>4)*4 + reg
#pragma unroll
    for (int t = 0; t < 4; ++t)
#pragma unroll
        for (int q = 0; q < 4; ++q)
            msgs[wr + hq * 4 + q][wc + t * 16 + lr] = fmaxf(acc[t][q], 0.f);
    __syncthreads();

    // ---- phase 2: GRU gates, all in registers ----
    float pr[4][4], pz[4][4], xn[4][4], hn[4][4];
    {
        float4 bxr = *(const float4*)(bihf + c0);
        float4 bhr = *(const float4*)(bhhf + c0);
        float4 bxz = *(const float4*)(bihf + 128 + c0);
        float4 bhz = *(const float4*)(bhhf + 128 + c0);
        float4 bxn = *(const float4*)(bihf + 256 + c0);
        float4 bhn = *(const float4*)(bhhf + 256 + c0);
#pragma unroll
        for (int r = 0; r < 4; ++r)
#pragma unroll
            for (int j = 0; j < 4; ++j) {
                pr[r][j] = f4c(bxr, j) + f4c(bhr, j);
                pz[r][j] = f4c(bxz, j) + f4c(bhz, j);
                xn[r][j] = f4c(bxn, j);
                hn[r][j] = f4c(bhn, j);
            }
    }

#pragma unroll 2
    for (int k = 0; k < HH; k += 4) {
        float4 mg[4], hg[4];
#pragma unroll
        for (int r = 0; r < 4; ++r) {
            mg[r] = *(const float4*)&msgs[r0 + r][k];
            hg[r] = *(const float4*)&hrs[r0 + r][k];
        }
#pragma unroll
        for (int kk = 0; kk < 4; ++kk) {
            const float* wb = WihT + (size_t)(k + kk) * 384 + c0;
            const float* hb = WhhT + (size_t)(k + kk) * 384 + c0;
            float4 wxr = *(const float4*)(wb);
            float4 wxz = *(const float4*)(wb + 128);
            float4 wxn = *(const float4*)(wb + 256);
            float4 whr = *(const float4*)(hb);
            float4 whz = *(const float4*)(hb + 128);
            float4 whn = *(const float4*)(hb + 256);
#pragma unroll
            for (int r = 0; r < 4; ++r) {
                float mv = f4c(mg[r], kk);
                float hv = f4c(hg[r], kk);
                pr[r][0] = fmaf(mv, wxr.x, fmaf(hv, whr.x, pr[r][0]));
                pr[r][1] = fmaf(mv, wxr.y, fmaf(hv, whr.y, pr[r][1]));
                pr[r][2] = fmaf(mv, wxr.z, fmaf(hv, whr.z, pr[r][2]));
                pr[r][3] = fmaf(mv, wxr.w, fmaf(hv, whr.w, pr[r][3]));
                pz[r][0] = fmaf(mv, wxz.x, fmaf(hv, whz.x, pz[r][0]));
                pz[r][1] = fmaf(mv, wxz.y, fmaf(hv, whz.y, pz[r][1]));
                pz[r][2] = fmaf(mv, wxz.z, fmaf(hv, whz.z, pz[r][2]));
                pz[r][3] = fmaf(mv, wxz.w, fmaf(hv, whz.w, pz[r][3]));
                xn[r][0] = fmaf(mv, wxn.x, xn[r][0]);
                xn[r][1] = fmaf(mv, wxn.y, xn[r][1]);
                xn[r][2] = fmaf(mv, wxn.z, xn[r][2]);
                xn[r][3] = fmaf(mv, wxn.w, xn[r][3]);
                hn[r][0] = fmaf(hv, whn.x, hn[r][0]);
                hn[r][1] = fmaf(hv, whn.y, hn[r][1]);
                hn[r][2] = fmaf(hv, whn.z, hn[r][2]);
                hn[r][3] = fmaf(hv, whn.w, hn[r][3]);
            }
        }
    }

    // ---- GRU combine + store ----
#pragma unroll
    for (int r = 0; r < 4; ++r) {
        float res[4];
#pragma unroll
        for (int j = 0; j < 4; ++j) {
            float rr = 1.f / (1.f + expf(-pr[r][j]));
            float zz = 1.f / (1.f + expf(-pz[r][j]));
            float nv = tanhf(xn[r][j] + rr * hn[r][j]);
            res[j] = (1.f - zz) * nv + zz * hrs[r0 + r][c0 + j];
        }
        size_t o = ((size_t)(b * NN + n0 + r0 + r)) * HH + c0;
        if constexpr (BF16) {
            ushort4 u;
            u.x = bf_rn(res[0]); u.y = bf_rn(res[1]); u.z = bf_rn(res[2]); u.w = bf_rn(res[3]);
            *(ushort4*)((ushort_t*)out + o) = u;
        } else {
            *(float4*)((float*)out + o) = make_float4(res[0], res[1], res[2], res[3]);
        }
    }
}

// ---------------------------------------------------------------------------
// diagnostic fill
// ---------------------------------------------------------------------------
__global__ void diag_kernel(float* __restrict__ out, float val, int nfill)
{
    int i = blockIdx.x * 256 + threadIdx.x;
    if (i < nfill) out[i] = val;
}

// ---------------------------------------------------------------------------
extern "C" void kernel_launch(void* const* d_in, const int* in_sizes, int n_in,
                              void* d_out, int out_size, void* d_ws, size_t ws_size,
                              hipStream_t stream)
{
    const int expected[10] = {BN * HH, BB * NN * NN, HH * HH, HH, HH * HH, HH,
                              3 * HH * HH, 3 * HH * HH, 3 * HH, 3 * HH};
    int bad = -1;
    if (n_in < 10) bad = 50;
    else {
        for (int i = 0; i < 10; ++i)
            if (in_sizes[i] != expected[i]) { bad = i; break; }
    }
    if (bad < 0 && out_size != BN * HH) bad = 60;
    if (bad >= 0) {
        float val = 10000.0f + 1000.0f * (float)bad;
        int nfill = out_size / 2;
        diag_kernel<<<(nfill + 255) / 256, 256, 0, stream>>>((float*)d_out, val, nfill);
        return;
    }

    const void* h   = d_in[0];
    const void* A   = d_in[1];
    const void* W1  = d_in[2];
    const void* b1  = d_in[3];
    const void* W2  = d_in[4];
    const void* b2  = d_in[5];
    const void* Wih = d_in[6];
    const void* Whh = d_in[7];
    const void* bih = d_in[8];
    const void* bhh = d_in[9];

    const size_t need_bf  = WS_M + (size_t)BN * HH * 2;    // mT_hi only
    const size_t need_f32 = WS_M + (size_t)BN * HH * 4;    // mT_hi + mT_lo
    if (ws_size < need_bf) {
        float val = 2000.0f + (float)(ws_size >> 10);
        int nfill = out_size / 2;
        diag_kernel<<<(nfill + 255) / 256, 256, 0, stream>>>((float*)d_out, val, nfill);
        return;
    }
    const bool split = (ws_size >= need_f32);
    int*  flag = (int*)d_ws;
    char* ws   = (char*)d_ws;

    detect_kernel<<<1, 256, 0, stream>>>((const ushort_t*)A, flag);

    prep_kernel<true ><<<64, 256, 0, stream>>>(flag, W1, b1, W2, b2, Wih, Whh, bih, bhh, ws);
    prep_kernel<false><<<64, 256, 0, stream>>>(flag, W1, b1, W2, b2, Wih, Whh, bih, bhh, ws);

    // bf16-input variants never need the split m
    mlp_kernel<true, false><<<BN / 32, 256, 0, stream>>>(flag, h, ws);
    if (split) {
        mlp_kernel<false, true ><<<BN / 32, 256, 0, stream>>>(flag, h, ws);
        fused_kernel<true,  false><<<BB * (NN / 32), 256, 0, stream>>>(flag, A, h, ws, d_out);
        fused_kernel<false, true ><<<BB * (NN / 32), 256, 0, stream>>>(flag, A, h, ws, d_out);
    } else {
        mlp_kernel<false, false><<<BN / 32, 256, 0, stream>>>(flag, h, ws);
        fused_kernel<true,  false><<<BB * (NN / 32), 256, 0, stream>>>(flag, A, h, ws, d_out);
        fused_kernel<false, false><<<BB * (NN / 32), 256, 0, stream>>>(flag, A, h, ws, d_out);
    }
}

// Round 4
// 391.651 us; speedup vs baseline: 1.2512x; 1.2512x over previous
//
#include <hip/hip_runtime.h>
#include <hip/hip_bf16.h>
#include <math.h>

#define BB 8
#define NN 2048
#define HH 128
#define BN (BB*NN)   // 16384

typedef unsigned short ushort_t;
typedef __attribute__((ext_vector_type(8))) short short8_t;
typedef __attribute__((ext_vector_type(4))) float f32x4_t;

// ---------------------------------------------------------------------------
// workspace layout (bytes).  Weights stored as bf16 hi/lo pairs in ORIGINAL
// [c][k] layout (k contiguous) = MFMA B-fragment native.  Biases fp32.
// ---------------------------------------------------------------------------
#define WS_FLAG   0
#define WS_W1H    4096
#define WS_W1L    (WS_W1H + 32768)      // 128*128*2
#define WS_W2H    (WS_W1L + 32768)
#define WS_W2L    (WS_W2H + 32768)
#define WS_WIHH   (WS_W2L + 32768)      // 384*128*2 = 98304
#define WS_WIHL   (WS_WIHH + 98304)
#define WS_WHHH   (WS_WIHL + 98304)
#define WS_WHHL   (WS_WHHH + 98304)
#define WS_B1     (WS_WHHL + 98304)     // 528384
#define WS_B2     (WS_B1 + 512)
#define WS_BIH    (WS_B2 + 512)
#define WS_BHH    (WS_BIH + 1536)       // ends at 532480
#define WS_M      532480                // mT_hi [8][128][2048] bf16 = 4 MiB
#define WS_MLO    (WS_M + 4194304)      // mT_lo = 4 MiB (fp32 split path)

template<bool BF16>
__device__ __forceinline__ float ldf(const void* p, size_t off) {
    if constexpr (BF16) return (float)((const __bf16*)p)[off];
    else                return ((const float*)p)[off];
}

__device__ __forceinline__ float f4c(const float4 v, int i) {
    switch (i) { case 0: return v.x; case 1: return v.y; case 2: return v.z; default: return v.w; }
}

__device__ __forceinline__ ushort_t bf_rn(float v) {   // round-to-nearest bf16 bits
    __bf16 b = (__bf16)v;
    return *(ushort_t*)&b;
}
__device__ __forceinline__ float bf_to_f(ushort_t u) {
    return __uint_as_float((unsigned)u << 16);
}
__device__ __forceinline__ float bfs_to_f(short s) {
    return __uint_as_float(((unsigned)(ushort_t)s) << 16);
}
__device__ __forceinline__ void split2(float v, ushort_t& hi, ushort_t& lo) {
    hi = bf_rn(v);
    lo = bf_rn(v - bf_to_f(hi));
}

__device__ __forceinline__ f32x4_t mfma16(short8_t a, short8_t b, f32x4_t c) {
    return __builtin_amdgcn_mfma_f32_16x16x32_bf16(a, b, c, 0, 0, 0);
}

// ---------------------------------------------------------------------------
// detect input dtype from A's bit patterns.
// bf16 U(0,1): every ushort <= 0x3F80.  fp32: ~37% of all ushorts exceed.
// ---------------------------------------------------------------------------
__global__ void detect_kernel(const ushort_t* __restrict__ Au, int* __restrict__ flag)
{
    __shared__ int cnt;
    if (threadIdx.x == 0) cnt = 0;
    __syncthreads();
    int c = 0;
    for (int i = threadIdx.x; i < 4096; i += 256)
        if (Au[i] > 0x3F80u) ++c;
    atomicAdd(&cnt, c);
    __syncthreads();
    if (threadIdx.x == 0) *flag = (cnt < 100) ? 1 : 0;   // 1 = bf16 inputs
}

// ---------------------------------------------------------------------------
// prep: split all weights into bf16 hi/lo (original [c][k] layout, k-contig)
// + widen biases to fp32.  For bf16 inputs lo comes out exactly 0.
// ---------------------------------------------------------------------------
template<bool BF16>
__global__ __launch_bounds__(256) void prep_kernel(
    const int* __restrict__ flag,
    const void* __restrict__ W1, const void* __restrict__ b1,
    const void* __restrict__ W2, const void* __restrict__ b2,
    const void* __restrict__ Wih, const void* __restrict__ Whh,
    const void* __restrict__ bih, const void* __restrict__ bhh,
    char* __restrict__ ws)
{
    if (*flag != (int)BF16) return;
    ushort_t* w1h = (ushort_t*)(ws + WS_W1H);
    ushort_t* w1l = (ushort_t*)(ws + WS_W1L);
    ushort_t* w2h = (ushort_t*)(ws + WS_W2H);
    ushort_t* w2l = (ushort_t*)(ws + WS_W2L);
    ushort_t* wihh = (ushort_t*)(ws + WS_WIHH);
    ushort_t* wihl = (ushort_t*)(ws + WS_WIHL);
    ushort_t* whhh = (ushort_t*)(ws + WS_WHHH);
    ushort_t* whhl = (ushort_t*)(ws + WS_WHHL);
    float* b1f  = (float*)(ws + WS_B1);
    float* b2f  = (float*)(ws + WS_B2);
    float* bihf = (float*)(ws + WS_BIH);
    float* bhhf = (float*)(ws + WS_BHH);

    int t = blockIdx.x * 256 + threadIdx.x;
    int nth = gridDim.x * 256;
    for (int i = t; i < HH * HH; i += nth) {
        ushort_t hi, lo;
        split2(ldf<BF16>(W1, i), hi, lo); w1h[i] = hi; w1l[i] = lo;
        split2(ldf<BF16>(W2, i), hi, lo); w2h[i] = hi; w2l[i] = lo;
    }
    for (int i = t; i < 3 * HH * HH; i += nth) {
        ushort_t hi, lo;
        split2(ldf<BF16>(Wih, i), hi, lo); wihh[i] = hi; wihl[i] = lo;
        split2(ldf<BF16>(Whh, i), hi, lo); whhh[i] = hi; whhl[i] = lo;
    }
    if (t < HH)     { b1f[t] = ldf<BF16>(b1, t);  b2f[t] = ldf<BF16>(b2, t); }
    if (t < 3 * HH) { bihf[t] = ldf<BF16>(bih, t); bhhf[t] = ldf<BF16>(bhh, t); }
}

// ---------------------------------------------------------------------------
// MLP via MFMA: m = relu(relu(h@W1^T+b1)@W2^T+b2).
// 32 rows/block, 4 waves; wave w: rows (w&1)*16..+15, col-tiles (w>>1)*4..+3.
// Frag mappings are the R2-verified ones: A lane=row, 8k at 8*(lane>>4);
// B lane=col; C/D col=lane&15, row=(lane>>4)*4+q.
// Exports mT[b][c][n] bf16 hi (+lo when SPLIT) for the msg kernel.
// ---------------------------------------------------------------------------
template<bool BF16, bool SPLIT>
__global__ __launch_bounds__(256) void mlp_kernel(
    const int* __restrict__ flag, const void* __restrict__ h,
    char* __restrict__ ws)
{
    if (*flag != (int)BF16) return;
    __shared__ float hf[32][132];
    __shared__ ushort_t m1h[32][264], m1l[32][264];

    const ushort_t* w1h = (const ushort_t*)(ws + WS_W1H);
    const ushort_t* w1l = (const ushort_t*)(ws + WS_W1L);
    const ushort_t* w2h = (const ushort_t*)(ws + WS_W2H);
    const ushort_t* w2l = (const ushort_t*)(ws + WS_W2L);
    const float* b1f = (const float*)(ws + WS_B1);
    const float* b2f = (const float*)(ws + WS_B2);
    ushort_t* mTh = (ushort_t*)(ws + WS_M);
    ushort_t* mTl = (ushort_t*)(ws + WS_MLO);

    const int tid = threadIdx.x;
    const int row0 = blockIdx.x * 32;

    // ---- stage h rows as fp32 LDS ----
    if constexpr (BF16) {
#pragma unroll
        for (int j = 0; j < 2; ++j) {
            int e = j * 256 + tid;             // 16B chunks of 8 bf16
            int r = e >> 4, c8 = (e & 15) * 8;
            short8_t v = *reinterpret_cast<const short8_t*>((const ushort_t*)h + (size_t)(row0 + r) * HH + c8);
#pragma unroll
            for (int q = 0; q < 8; ++q) hf[r][c8 + q] = bfs_to_f(v[q]);
        }
    } else {
#pragma unroll
        for (int j = 0; j < 4; ++j) {
            int e = j * 256 + tid;
            int r = e >> 5, c4 = (e & 31) * 4;
            *(float4*)&hf[r][c4] = *reinterpret_cast<const float4*>((const float*)h + (size_t)(row0 + r) * HH + c4);
        }
    }
    __syncthreads();

    const int lane = tid & 63, wv = tid >> 6;
    const int lr = lane & 15, hq = lane >> 4;
    const int rt = wv & 1, ct0 = (wv >> 1) * 4;

    // ---- layer 1 ----
    f32x4_t acc[4];
#pragma unroll
    for (int c = 0; c < 4; ++c) { acc[c][0] = 0.f; acc[c][1] = 0.f; acc[c][2] = 0.f; acc[c][3] = 0.f; }

    for (int k0 = 0; k0 < HH; k0 += 32) {
        // A frags (hi/lo) from fp32 LDS
        short8_t ahh, ahl;
        {
            float4 f0 = *(const float4*)&hf[rt * 16 + lr][k0 + 8 * hq];
            float4 f1 = *(const float4*)&hf[rt * 16 + lr][k0 + 8 * hq + 4];
#pragma unroll
            for (int j = 0; j < 4; ++j) {
                ushort_t hi, lo;
                split2(f4c(f0, j), hi, lo); ahh[j] = (short)hi; ahl[j] = (short)lo;
                split2(f4c(f1, j), hi, lo); ahh[j + 4] = (short)hi; ahl[j + 4] = (short)lo;
            }
        }
#pragma unroll
        for (int c = 0; c < 4; ++c) {
            size_t wo = (size_t)((ct0 + c) * 16 + lr) * HH + k0 + 8 * hq;
            short8_t bh = *reinterpret_cast<const short8_t*>(w1h + wo);
            acc[c] = mfma16(ahh, bh, acc[c]);
            if constexpr (!BF16) {
                short8_t bl = *reinterpret_cast<const short8_t*>(w1l + wo);
                acc[c] = mfma16(ahl, bh, acc[c]);
                acc[c] = mfma16(ahh, bl, acc[c]);
            }
        }
    }
    // epilogue 1: bias+relu -> split bf16 -> LDS
#pragma unroll
    for (int c = 0; c < 4; ++c) {
        int col = (ct0 + c) * 16 + lr;
        float bv = b1f[col];
#pragma unroll
        for (int q = 0; q < 4; ++q) {
            int row = rt * 16 + hq * 4 + q;
            float v = fmaxf(acc[c][q] + bv, 0.f);
            ushort_t hi, lo;
            split2(v, hi, lo);
            m1h[row][col] = hi;
            if constexpr (!BF16) m1l[row][col] = lo;
        }
    }
    __syncthreads();

    // ---- layer 2 ----
    f32x4_t acc2[4];
#pragma unroll
    for (int c = 0; c < 4; ++c) { acc2[c][0] = 0.f; acc2[c][1] = 0.f; acc2[c][2] = 0.f; acc2[c][3] = 0.f; }

    for (int k0 = 0; k0 < HH; k0 += 32) {
        short8_t amh = *reinterpret_cast<const short8_t*>(&m1h[rt * 16 + lr][k0 + 8 * hq]);
        short8_t aml;
        if constexpr (!BF16) aml = *reinterpret_cast<const short8_t*>(&m1l[rt * 16 + lr][k0 + 8 * hq]);
#pragma unroll
        for (int c = 0; c < 4; ++c) {
            size_t wo = (size_t)((ct0 + c) * 16 + lr) * HH + k0 + 8 * hq;
            short8_t bh = *reinterpret_cast<const short8_t*>(w2h + wo);
            acc2[c] = mfma16(amh, bh, acc2[c]);
            if constexpr (!BF16) {
                short8_t bl = *reinterpret_cast<const short8_t*>(w2l + wo);
                acc2[c] = mfma16(aml, bh, acc2[c]);
                acc2[c] = mfma16(amh, bl, acc2[c]);
            }
        }
    }
    // epilogue 2: bias+relu -> split -> mT[b][c][n]
    {
        int bb = row0 >> 11, nloc0 = row0 & 2047;
#pragma unroll
        for (int c = 0; c < 4; ++c) {
            int col = (ct0 + c) * 16 + lr;
            float bv = b2f[col];
#pragma unroll
            for (int q = 0; q < 4; ++q) {
                int row = rt * 16 + hq * 4 + q;
                float v = fmaxf(acc2[c][q] + bv, 0.f);
                ushort_t hi, lo;
                split2(v, hi, lo);
                size_t o = (size_t)(bb * 128 + col) * NN + nloc0 + row;
                mTh[o] = hi;
                if constexpr (SPLIT) mTl[o] = lo;
            }
        }
    }
}

// ---------------------------------------------------------------------------
// msg = relu(A@m) via MFMA, LDS-free (R2-verified structure).  Result packed
// bf16 hi/lo INTO THE OUTPUT BUFFER's own row slot (fp32 row = 512B = 256B hi
// + 256B lo; bf16 row = 256B = hi only).  gru_kernel reads its own rows and
// then overwrites them -- no extra workspace, no cross-block hazard.
// ---------------------------------------------------------------------------
template<bool BF16, bool SPLIT>
__global__ __launch_bounds__(256) void msg_kernel(
    const int* __restrict__ flag, const void* __restrict__ A,
    const char* __restrict__ ws, void* __restrict__ out)
{
    if (*flag != (int)BF16) return;
    const ushort_t* mTh = (const ushort_t*)(ws + WS_M);
    const ushort_t* mTl = (const ushort_t*)(ws + WS_MLO);

    const int tid = threadIdx.x;
    const int b = blockIdx.x & 7, rtile = blockIdx.x >> 3;
    const int n0 = rtile * 32;
    const int lane = tid & 63, wv = tid >> 6;
    const int lr = lane & 15, hq = lane >> 4;
    const int wr = (wv & 1) * 16, wc = (wv >> 1) * 64;

    f32x4_t acc[4];
#pragma unroll
    for (int t = 0; t < 4; ++t) { acc[t][0] = 0.f; acc[t][1] = 0.f; acc[t][2] = 0.f; acc[t][3] = 0.f; }

    const size_t abase = ((size_t)(b * NN + n0 + wr + lr)) * NN + 8 * hq;   // A[row][k]
    const size_t mbase = ((size_t)(b * 128 + wc + lr)) * NN + 8 * hq;       // mT[col][k]

#pragma unroll 2
    for (int k0 = 0; k0 < NN; k0 += 32) {
        short8_t ah, al;
        if constexpr (BF16) {
            ah = *reinterpret_cast<const short8_t*>((const ushort_t*)A + abase + k0);
        } else {
            const float* ap = (const float*)A + abase + k0;
            float4 a0 = *reinterpret_cast<const float4*>(ap);
            float4 a1 = *reinterpret_cast<const float4*>(ap + 4);
#pragma unroll
            for (int j = 0; j < 4; ++j) {
                ushort_t hi, lo;
                split2(f4c(a0, j), hi, lo); ah[j] = (short)hi; al[j] = (short)lo;
                split2(f4c(a1, j), hi, lo); ah[j + 4] = (short)hi; al[j + 4] = (short)lo;
            }
        }
#pragma unroll
        for (int t = 0; t < 4; ++t) {
            short8_t bh = *reinterpret_cast<const short8_t*>(mTh + mbase + (size_t)t * 16 * NN + k0);
            acc[t] = mfma16(ah, bh, acc[t]);
            if constexpr (!BF16) {
                acc[t] = mfma16(al, bh, acc[t]);     // A_lo * m_hi
                if constexpr (SPLIT) {
                    short8_t bl = *reinterpret_cast<const short8_t*>(mTl + mbase + (size_t)t * 16 * NN + k0);
                    acc[t] = mfma16(ah, bl, acc[t]); // A_hi * m_lo
                }
            }
        }
    }

    // packed store: C/D layout col=lane&15, row=(lane>>4)*4+q
    char* ob = (char*)out;
#pragma unroll
    for (int t = 0; t < 4; ++t)
#pragma unroll
        for (int q = 0; q < 4; ++q) {
            int row = wr + hq * 4 + q, col = wc + t * 16 + lr;
            size_t gr = (size_t)(b * NN + n0 + row);
            float v = fmaxf(acc[t][q], 0.f);
            if constexpr (BF16) {
                *(ushort_t*)(ob + gr * 256 + col * 2) = bf_rn(v);
            } else {
                ushort_t hi, lo;
                split2(v, hi, lo);
                *(ushort_t*)(ob + gr * 512 + col * 2) = hi;
                *(ushort_t*)(ob + gr * 512 + 256 + col * 2) = lo;
            }
        }
}

// ---------------------------------------------------------------------------
// GRU via MFMA.  32 rows/block; wave w owns cols w*32..+31 of ALL THREE gates
// for BOTH gemms -> r/z/n combine is per-lane in registers (no gX/gH arrays,
// no scalar accumulator spill).  24 f32x4 accumulators/lane.
// waves_per_eu(1,2): pin allocator target to 2 waves/SIMD (grid gives exactly
// that) so it stops squeezing VGPRs below the live set.
// ---------------------------------------------------------------------------
template<bool BF16>
__global__ __launch_bounds__(256) __attribute__((amdgpu_waves_per_eu(1, 2)))
void gru_kernel(
    const int* __restrict__ flag, const void* __restrict__ h,
    const char* __restrict__ ws, void* __restrict__ out)
{
    if (*flag != (int)BF16) return;
    __shared__ ushort_t msgh[32][264], msgl[32][264];
    __shared__ float hf[32][132];

    const ushort_t* wihh = (const ushort_t*)(ws + WS_WIHH);
    const ushort_t* wihl = (const ushort_t*)(ws + WS_WIHL);
    const ushort_t* whhh = (const ushort_t*)(ws + WS_WHHH);
    const ushort_t* whhl = (const ushort_t*)(ws + WS_WHHL);
    const float* bihf = (const float*)(ws + WS_BIH);
    const float* bhhf = (const float*)(ws + WS_BHH);

    const int tid = threadIdx.x;
    const int row0 = blockIdx.x * 32;
    char* ob = (char*)out;

    // ---- stage packed msg (from out rows) ----
    if constexpr (BF16) {
#pragma unroll
        for (int j = 0; j < 2; ++j) {
            int e = j * 256 + tid;
            int r = e >> 4, c8 = (e & 15) * 8;
            short8_t v = *reinterpret_cast<const short8_t*>(ob + (size_t)(row0 + r) * 256 + c8 * 2);
            *(short8_t*)&msgh[r][c8] = v;
        }
    } else {
#pragma unroll
        for (int j = 0; j < 4; ++j) {
            int e = j * 256 + tid;
            int r = e >> 5, off = (e & 31) * 16;   // byte offset within 512B row
            short8_t v = *reinterpret_cast<const short8_t*>(ob + (size_t)(row0 + r) * 512 + off);
            if (off < 256) *(short8_t*)&msgh[r][off >> 1] = v;
            else           *(short8_t*)&msgl[r][(off - 256) >> 1] = v;
        }
    }
    // ---- stage h rows as fp32 ----
    if constexpr (BF16) {
#pragma unroll
        for (int j = 0; j < 2; ++j) {
            int e = j * 256 + tid;
            int r = e >> 4, c8 = (e & 15) * 8;
            short8_t v = *reinterpret_cast<const short8_t*>((const ushort_t*)h + (size_t)(row0 + r) * HH + c8);
#pragma unroll
            for (int q = 0; q < 8; ++q) hf[r][c8 + q] = bfs_to_f(v[q]);
        }
    } else {
#pragma unroll
        for (int j = 0; j < 4; ++j) {
            int e = j * 256 + tid;
            int r = e >> 5, c4 = (e & 31) * 4;
            *(float4*)&hf[r][c4] = *reinterpret_cast<const float4*>((const float*)h + (size_t)(row0 + r) * HH + c4);
        }
    }
    __syncthreads();

    const int lane = tid & 63, wv = tid >> 6;
    const int lr = lane & 15, hq = lane >> 4;
    const int cw0 = wv * 32;

    f32x4_t accx[2][3][2], acch[2][3][2];
#pragma unroll
    for (int rt = 0; rt < 2; ++rt)
#pragma unroll
        for (int g = 0; g < 3; ++g)
#pragma unroll
            for (int ct = 0; ct < 2; ++ct) {
                accx[rt][g][ct][0] = 0.f; accx[rt][g][ct][1] = 0.f;
                accx[rt][g][ct][2] = 0.f; accx[rt][g][ct][3] = 0.f;
                acch[rt][g][ct][0] = 0.f; acch[rt][g][ct][1] = 0.f;
                acch[rt][g][ct][2] = 0.f; acch[rt][g][ct][3] = 0.f;
            }

    for (int k0 = 0; k0 < HH; k0 += 32) {
        // A-frags: msg (bf16 hi/lo from LDS) and h (pack from fp32)
        short8_t amh[2], aml[2], ahh[2], ahl[2];
#pragma unroll
        for (int rt = 0; rt < 2; ++rt) {
            amh[rt] = *reinterpret_cast<const short8_t*>(&msgh[rt * 16 + lr][k0 + 8 * hq]);
            if constexpr (!BF16)
                aml[rt] = *reinterpret_cast<const short8_t*>(&msgl[rt * 16 + lr][k0 + 8 * hq]);
            float4 f0 = *(const float4*)&hf[rt * 16 + lr][k0 + 8 * hq];
            float4 f1 = *(const float4*)&hf[rt * 16 + lr][k0 + 8 * hq + 4];
#pragma unroll
            for (int j = 0; j < 4; ++j) {
                ushort_t hi, lo;
                split2(f4c(f0, j), hi, lo); ahh[rt][j] = (short)hi; ahl[rt][j] = (short)lo;
                split2(f4c(f1, j), hi, lo); ahh[rt][j + 4] = (short)hi; ahl[rt][j + 4] = (short)lo;
            }
        }
#pragma unroll
        for (int g = 0; g < 3; ++g)
#pragma unroll
            for (int ct = 0; ct < 2; ++ct) {
                size_t wo = (size_t)(g * 128 + cw0 + ct * 16 + lr) * HH + k0 + 8 * hq;
                short8_t bxh = *reinterpret_cast<const short8_t*>(wihh + wo);
                short8_t bhh2 = *reinterpret_cast<const short8_t*>(whhh + wo);
                short8_t bxl, bhl2;
                if constexpr (!BF16) {
                    bxl  = *reinterpret_cast<const short8_t*>(wihl + wo);
                    bhl2 = *reinterpret_cast<const short8_t*>(whhl + wo);
                }
#pragma unroll
                for (int rt = 0; rt < 2; ++rt) {
                    accx[rt][g][ct] = mfma16(amh[rt], bxh, accx[rt][g][ct]);
                    acch[rt][g][ct] = mfma16(ahh[rt], bhh2, acch[rt][g][ct]);
                    if constexpr (!BF16) {
                        accx[rt][g][ct] = mfma16(aml[rt], bxh, accx[rt][g][ct]);
                        accx[rt][g][ct] = mfma16(amh[rt], bxl, accx[rt][g][ct]);
                        acch[rt][g][ct] = mfma16(ahl[rt], bhh2, acch[rt][g][ct]);
                        acch[rt][g][ct] = mfma16(ahh[rt], bhl2, acch[rt][g][ct]);
                    }
                }
            }
    }

    // ---- combine + store (per-lane, no LDS materialization) ----
#pragma unroll
    for (int rt = 0; rt < 2; ++rt)
#pragma unroll
        for (int ct = 0; ct < 2; ++ct) {
            int col = cw0 + ct * 16 + lr;
            float brx = bihf[col],       brh = bhhf[col];
            float bzx = bihf[128 + col], bzh = bhhf[128 + col];
            float bnx = bihf[256 + col], bnh = bhhf[256 + col];
#pragma unroll
            for (int q = 0; q < 4; ++q) {
                int row = rt * 16 + hq * 4 + q;
                float gr_ = (accx[rt][0][ct][q] + brx) + (acch[rt][0][ct][q] + brh);
                float gz_ = (accx[rt][1][ct][q] + bzx) + (acch[rt][1][ct][q] + bzh);
                float gxn = accx[rt][2][ct][q] + bnx;
                float ghn = acch[rt][2][ct][q] + bnh;
                float rr = 1.f / (1.f + expf(-gr_));
                float zz = 1.f / (1.f + expf(-gz_));
                float nv = tanhf(gxn + rr * ghn);
                float hv = hf[row][col];
                float res = (1.f - zz) * nv + zz * hv;
                size_t o = (size_t)(row0 + row) * HH + col;
                if constexpr (BF16) ((ushort_t*)out)[o] = bf_rn(res);
                else                ((float*)out)[o]    = res;
            }
        }
}

// ---------------------------------------------------------------------------
// diagnostic fill
// ---------------------------------------------------------------------------
__global__ void diag_kernel(float* __restrict__ out, float val, int nfill)
{
    int i = blockIdx.x * 256 + threadIdx.x;
    if (i < nfill) out[i] = val;
}

// ---------------------------------------------------------------------------
extern "C" void kernel_launch(void* const* d_in, const int* in_sizes, int n_in,
                              void* d_out, int out_size, void* d_ws, size_t ws_size,
                              hipStream_t stream)
{
    const int expected[10] = {BN * HH, BB * NN * NN, HH * HH, HH, HH * HH, HH,
                              3 * HH * HH, 3 * HH * HH, 3 * HH, 3 * HH};
    int bad = -1;
    if (n_in < 10) bad = 50;
    else {
        for (int i = 0; i < 10; ++i)
            if (in_sizes[i] != expected[i]) { bad = i; break; }
    }
    if (bad < 0 && out_size != BN * HH) bad = 60;
    if (bad >= 0) {
        float val = 10000.0f + 1000.0f * (float)bad;
        int nfill = out_size / 2;
        diag_kernel<<<(nfill + 255) / 256, 256, 0, stream>>>((float*)d_out, val, nfill);
        return;
    }

    const void* h   = d_in[0];
    const void* A   = d_in[1];
    const void* W1  = d_in[2];
    const void* b1  = d_in[3];
    const void* W2  = d_in[4];
    const void* b2  = d_in[5];
    const void* Wih = d_in[6];
    const void* Whh = d_in[7];
    const void* bih = d_in[8];
    const void* bhh = d_in[9];

    const size_t need_bf  = WS_M + (size_t)BN * HH * 2;    // mT_hi only
    const size_t need_f32 = WS_M + (size_t)BN * HH * 4;    // mT_hi + mT_lo
    if (ws_size < need_bf) {
        float val = 2000.0f + (float)(ws_size >> 10);
        int nfill = out_size / 2;
        diag_kernel<<<(nfill + 255) / 256, 256, 0, stream>>>((float*)d_out, val, nfill);
        return;
    }
    const bool split = (ws_size >= need_f32);
    int*  flag = (int*)d_ws;
    char* ws   = (char*)d_ws;

    detect_kernel<<<1, 256, 0, stream>>>((const ushort_t*)A, flag);

    prep_kernel<true ><<<64, 256, 0, stream>>>(flag, W1, b1, W2, b2, Wih, Whh, bih, bhh, ws);
    prep_kernel<false><<<64, 256, 0, stream>>>(flag, W1, b1, W2, b2, Wih, Whh, bih, bhh, ws);

    mlp_kernel<true, false><<<BN / 32, 256, 0, stream>>>(flag, h, ws);
    if (split) mlp_kernel<false, true ><<<BN / 32, 256, 0, stream>>>(flag, h, ws);
    else       mlp_kernel<false, false><<<BN / 32, 256, 0, stream>>>(flag, h, ws);

    msg_kernel<true, false><<<BB * (NN / 32), 256, 0, stream>>>(flag, A, ws, d_out);
    if (split) msg_kernel<false, true ><<<BB * (NN / 32), 256, 0, stream>>>(flag, A, ws, d_out);
    else       msg_kernel<false, false><<<BB * (NN / 32), 256, 0, stream>>>(flag, A, ws, d_out);

    gru_kernel<true ><<<BN / 32, 256, 0, stream>>>(flag, h, ws, d_out);
    gru_kernel<false><<<BN / 32, 256, 0, stream>>>(flag, h, ws, d_out);
}

// Round 5
// 316.946 us; speedup vs baseline: 1.5461x; 1.2357x over previous
//
#include <hip/hip_runtime.h>
#include <hip/hip_bf16.h>
#include <math.h>

#define BB 8
#define NN 2048
#define HH 128
#define BN (BB*NN)   // 16384

typedef unsigned short ushort_t;
typedef __attribute__((ext_vector_type(8))) short short8_t;
typedef __attribute__((ext_vector_type(4))) float f32x4_t;

// ---------------------------------------------------------------------------
// workspace layout (bytes).  All B-operand matrices stored FRAGMENT-LINEAR:
// for each (kstep=k/32, colgroup=c/16): 64 lanes x 8 bf16 contiguous, so a
// wave's MFMA B-frag load is one 1KB contiguous read (no 16-line scatter).
// po(c,k) = (((k>>5)*NCG + (c>>4))*64 + (c&15) + 16*((k>>3)&3))*8 + (k&7)
// ---------------------------------------------------------------------------
#define WS_FLAG   0
#define WS_W1H    4096
#define WS_W1L    (WS_W1H + 32768)      // 128*128*2
#define WS_W2H    (WS_W1L + 32768)
#define WS_W2L    (WS_W2H + 32768)
#define WS_WIHH   (WS_W2L + 32768)      // 384*128*2 = 98304
#define WS_WIHL   (WS_WIHH + 98304)
#define WS_WHHH   (WS_WIHL + 98304)
#define WS_WHHL   (WS_WHHH + 98304)
#define WS_B1     (WS_WHHL + 98304)     // 528384
#define WS_B2     (WS_B1 + 512)
#define WS_BIH    (WS_B2 + 512)
#define WS_BHH    (WS_BIH + 1536)       // ends at 532480
#define WS_M      532480                // mT packed hi: [8][64 ks][8 cg][64][8] = 4 MiB
#define WS_MLO    (WS_M + 4194304)      // mT packed lo = 4 MiB (fp32 split path)

template<bool BF16>
__device__ __forceinline__ float ldf(const void* p, size_t off) {
    if constexpr (BF16) return (float)((const __bf16*)p)[off];
    else                return ((const float*)p)[off];
}

__device__ __forceinline__ float f4c(const float4 v, int i) {
    switch (i) { case 0: return v.x; case 1: return v.y; case 2: return v.z; default: return v.w; }
}

__device__ __forceinline__ ushort_t bf_rn(float v) {
    __bf16 b = (__bf16)v;
    return *(ushort_t*)&b;
}
__device__ __forceinline__ float bf_to_f(ushort_t u) {
    return __uint_as_float((unsigned)u << 16);
}
__device__ __forceinline__ float bfs_to_f(short s) {
    return __uint_as_float(((unsigned)(ushort_t)s) << 16);
}
__device__ __forceinline__ void split2(float v, ushort_t& hi, ushort_t& lo) {
    hi = bf_rn(v);
    lo = bf_rn(v - bf_to_f(hi));
}

__device__ __forceinline__ f32x4_t mfma16(short8_t a, short8_t b, f32x4_t c) {
    return __builtin_amdgcn_mfma_f32_16x16x32_bf16(a, b, c, 0, 0, 0);
}

// ---------------------------------------------------------------------------
// detect input dtype from A's bit patterns.
// ---------------------------------------------------------------------------
__global__ void detect_kernel(const ushort_t* __restrict__ Au, int* __restrict__ flag)
{
    __shared__ int cnt;
    if (threadIdx.x == 0) cnt = 0;
    __syncthreads();
    int c = 0;
    for (int i = threadIdx.x; i < 4096; i += 256)
        if (Au[i] > 0x3F80u) ++c;
    atomicAdd(&cnt, c);
    __syncthreads();
    if (threadIdx.x == 0) *flag = (cnt < 100) ? 1 : 0;   // 1 = bf16 inputs
}

// ---------------------------------------------------------------------------
// prep: split weights into bf16 hi/lo, packed fragment-linear.
// ---------------------------------------------------------------------------
template<bool BF16>
__device__ void prep_body(
    const void* W1, const void* b1, const void* W2, const void* b2,
    const void* Wih, const void* Whh, const void* bih, const void* bhh,
    char* ws)
{
    ushort_t* w1h = (ushort_t*)(ws + WS_W1H);
    ushort_t* w1l = (ushort_t*)(ws + WS_W1L);
    ushort_t* w2h = (ushort_t*)(ws + WS_W2H);
    ushort_t* w2l = (ushort_t*)(ws + WS_W2L);
    ushort_t* wihh = (ushort_t*)(ws + WS_WIHH);
    ushort_t* wihl = (ushort_t*)(ws + WS_WIHL);
    ushort_t* whhh = (ushort_t*)(ws + WS_WHHH);
    ushort_t* whhl = (ushort_t*)(ws + WS_WHHL);
    float* b1f  = (float*)(ws + WS_B1);
    float* b2f  = (float*)(ws + WS_B2);
    float* bihf = (float*)(ws + WS_BIH);
    float* bhhf = (float*)(ws + WS_BHH);

    int t = blockIdx.x * 256 + threadIdx.x;
    int nth = gridDim.x * 256;
    for (int i = t; i < HH * HH; i += nth) {
        int c = i >> 7, k = i & 127;
        int po = (((k >> 5) * 8 + (c >> 4)) * 64 + (c & 15) + 16 * ((k >> 3) & 3)) * 8 + (k & 7);
        ushort_t hi, lo;
        split2(ldf<BF16>(W1, i), hi, lo); w1h[po] = hi; w1l[po] = lo;
        split2(ldf<BF16>(W2, i), hi, lo); w2h[po] = hi; w2l[po] = lo;
    }
    for (int i = t; i < 3 * HH * HH; i += nth) {
        int c = i >> 7, k = i & 127;
        int po = (((k >> 5) * 24 + (c >> 4)) * 64 + (c & 15) + 16 * ((k >> 3) & 3)) * 8 + (k & 7);
        ushort_t hi, lo;
        split2(ldf<BF16>(Wih, i), hi, lo); wihh[po] = hi; wihl[po] = lo;
        split2(ldf<BF16>(Whh, i), hi, lo); whhh[po] = hi; whhl[po] = lo;
    }
    if (t < HH)     { b1f[t] = ldf<BF16>(b1, t);  b2f[t] = ldf<BF16>(b2, t); }
    if (t < 3 * HH) { bihf[t] = ldf<BF16>(bih, t); bhhf[t] = ldf<BF16>(bhh, t); }
}

__global__ __launch_bounds__(256) void prep_kernel(
    const int* __restrict__ flag,
    const void* W1, const void* b1, const void* W2, const void* b2,
    const void* Wih, const void* Whh, const void* bih, const void* bhh,
    char* __restrict__ ws)
{
    if (*flag) prep_body<true >(W1, b1, W2, b2, Wih, Whh, bih, bhh, ws);
    else       prep_body<false>(W1, b1, W2, b2, Wih, Whh, bih, bhh, ws);
}

// ---------------------------------------------------------------------------
// MLP via MFMA; weights from packed frag-linear; exports mT packed
// frag-linear (hi + lo when SPLIT) for the msg kernel.
// ---------------------------------------------------------------------------
template<bool BF16, bool SPLIT>
__device__ void mlp_body(char* smem, const void* h, char* ws)
{
    float    (*hf)[132]  = (float(*)[132])smem;             // 16896 B
    ushort_t (*m1h)[264] = (ushort_t(*)[264])(smem + 16896);
    ushort_t (*m1l)[264] = (ushort_t(*)[264])(smem + 33792);

    const ushort_t* w1h = (const ushort_t*)(ws + WS_W1H);
    const ushort_t* w1l = (const ushort_t*)(ws + WS_W1L);
    const ushort_t* w2h = (const ushort_t*)(ws + WS_W2H);
    const ushort_t* w2l = (const ushort_t*)(ws + WS_W2L);
    const float* b1f = (const float*)(ws + WS_B1);
    const float* b2f = (const float*)(ws + WS_B2);
    ushort_t* mTh = (ushort_t*)(ws + WS_M);
    ushort_t* mTl = (ushort_t*)(ws + WS_MLO);

    const int tid = threadIdx.x;
    const int row0 = blockIdx.x * 32;

    // stage h rows as fp32
    if constexpr (BF16) {
#pragma unroll
        for (int j = 0; j < 2; ++j) {
            int e = j * 256 + tid;
            int r = e >> 4, c8 = (e & 15) * 8;
            short8_t v = *reinterpret_cast<const short8_t*>((const ushort_t*)h + (size_t)(row0 + r) * HH + c8);
#pragma unroll
            for (int q = 0; q < 8; ++q) hf[r][c8 + q] = bfs_to_f(v[q]);
        }
    } else {
#pragma unroll
        for (int j = 0; j < 4; ++j) {
            int e = j * 256 + tid;
            int r = e >> 5, c4 = (e & 31) * 4;
            *(float4*)&hf[r][c4] = *reinterpret_cast<const float4*>((const float*)h + (size_t)(row0 + r) * HH + c4);
        }
    }
    __syncthreads();

    const int lane = tid & 63, wv = tid >> 6;
    const int lr = lane & 15, hq = lane >> 4;
    const int rt = wv & 1, ct0 = (wv >> 1) * 4;

    // ---- layer 1 ----
    f32x4_t acc[4];
#pragma unroll
    for (int c = 0; c < 4; ++c) { acc[c][0] = 0.f; acc[c][1] = 0.f; acc[c][2] = 0.f; acc[c][3] = 0.f; }

    for (int k0 = 0; k0 < HH; k0 += 32) {
        short8_t ahh, ahl;
        {
            float4 f0 = *(const float4*)&hf[rt * 16 + lr][k0 + 8 * hq];
            float4 f1 = *(const float4*)&hf[rt * 16 + lr][k0 + 8 * hq + 4];
#pragma unroll
            for (int j = 0; j < 4; ++j) {
                ushort_t hi, lo;
                split2(f4c(f0, j), hi, lo); ahh[j] = (short)hi; ahl[j] = (short)lo;
                split2(f4c(f1, j), hi, lo); ahh[j + 4] = (short)hi; ahl[j + 4] = (short)lo;
            }
        }
        const int ks = k0 >> 5;
#pragma unroll
        for (int c = 0; c < 4; ++c) {
            size_t po = ((size_t)(ks * 8 + ct0 + c)) * 512 + (size_t)lane * 8;
            short8_t bh = *reinterpret_cast<const short8_t*>(w1h + po);
            acc[c] = mfma16(ahh, bh, acc[c]);
            if constexpr (!BF16) {
                short8_t bl = *reinterpret_cast<const short8_t*>(w1l + po);
                acc[c] = mfma16(ahl, bh, acc[c]);
                acc[c] = mfma16(ahh, bl, acc[c]);
            }
        }
    }
#pragma unroll
    for (int c = 0; c < 4; ++c) {
        int col = (ct0 + c) * 16 + lr;
        float bv = b1f[col];
#pragma unroll
        for (int q = 0; q < 4; ++q) {
            int row = rt * 16 + hq * 4 + q;
            float v = fmaxf(acc[c][q] + bv, 0.f);
            ushort_t hi, lo;
            split2(v, hi, lo);
            m1h[row][col] = hi;
            if constexpr (!BF16) m1l[row][col] = lo;
        }
    }
    __syncthreads();

    // ---- layer 2 ----
    f32x4_t acc2[4];
#pragma unroll
    for (int c = 0; c < 4; ++c) { acc2[c][0] = 0.f; acc2[c][1] = 0.f; acc2[c][2] = 0.f; acc2[c][3] = 0.f; }

    for (int k0 = 0; k0 < HH; k0 += 32) {
        short8_t amh = *reinterpret_cast<const short8_t*>(&m1h[rt * 16 + lr][k0 + 8 * hq]);
        short8_t aml;
        if constexpr (!BF16) aml = *reinterpret_cast<const short8_t*>(&m1l[rt * 16 + lr][k0 + 8 * hq]);
        const int ks = k0 >> 5;
#pragma unroll
        for (int c = 0; c < 4; ++c) {
            size_t po = ((size_t)(ks * 8 + ct0 + c)) * 512 + (size_t)lane * 8;
            short8_t bh = *reinterpret_cast<const short8_t*>(w2h + po);
            acc2[c] = mfma16(amh, bh, acc2[c]);
            if constexpr (!BF16) {
                short8_t bl = *reinterpret_cast<const short8_t*>(w2l + po);
                acc2[c] = mfma16(aml, bh, acc2[c]);
                acc2[c] = mfma16(amh, bl, acc2[c]);
            }
        }
    }
    // epilogue 2: bias+relu -> split -> packed mT
    {
        const int bb = row0 >> 11, nb = row0 & 2047;
#pragma unroll
        for (int c = 0; c < 4; ++c) {
            int col = (ct0 + c) * 16 + lr;
            float bv = b2f[col];
#pragma unroll
            for (int q = 0; q < 4; ++q) {
                int nn = nb + rt * 16 + hq * 4 + q;
                float v = fmaxf(acc2[c][q] + bv, 0.f);
                ushort_t hi, lo;
                split2(v, hi, lo);
                size_t po = (((size_t)(bb * 64 + (nn >> 5)) * 8 + (ct0 + c)) * 64
                             + lr + 16 * ((nn >> 3) & 3)) * 8 + (nn & 7);
                mTh[po] = hi;
                if constexpr (SPLIT) mTl[po] = lo;
            }
        }
    }
}

template<bool SPLIT>
__global__ __launch_bounds__(256) void mlp_kernel(
    const int* __restrict__ flag, const void* __restrict__ h, char* __restrict__ ws)
{
    __shared__ __align__(16) char smem[50688];
    if (*flag) mlp_body<true, false>(smem, h, ws);
    else       mlp_body<false, SPLIT>(smem, h, ws);
}

// ---------------------------------------------------------------------------
// msg = relu(A@m) via MFMA.  A: LDS-staged per 64-k tile (coalesced global
// reads, prefetched one tile ahead so HBM latency hides under compute).
// mT: packed frag-linear -> every B-frag load is 1KB contiguous.
// Result packed bf16 hi/lo into the output buffer's own row slot (as R4).
// ---------------------------------------------------------------------------
template<bool BF16, bool SPLIT>
__device__ void msg_body(char* smem, const void* A, const char* ws, void* out)
{
    ushort_t (*As_h)[72] = (ushort_t(*)[72])smem;           // 4608 B
    ushort_t (*As_l)[72] = (ushort_t(*)[72])(smem + 4608);  // 4608 B
    const ushort_t* mThp = (const ushort_t*)(ws + WS_M);
    const ushort_t* mTlp = (const ushort_t*)(ws + WS_MLO);

    const int tid = threadIdx.x;
    const int b = blockIdx.x & 7, rtile = blockIdx.x >> 3;
    const int n0 = rtile * 32;
    const int lane = tid & 63, wv = tid >> 6;
    const int lr = lane & 15, hq = lane >> 4;
    const int wr = (wv & 1) * 16, wc4 = (wv >> 1) * 4;   // col-group base (x16 cols)

    f32x4_t acc[4];
#pragma unroll
    for (int t = 0; t < 4; ++t) { acc[t][0] = 0.f; acc[t][1] = 0.f; acc[t][2] = 0.f; acc[t][3] = 0.f; }

    // staging index maps (constant per thread)
    const int er0 = tid >> 4, ec0 = (tid & 15) * 4;      // fp32: 2 units of float4
    const int br_ = tid >> 3, bc_ = (tid & 7) * 8;       // bf16: 1 unit of 8 bf16

    float4 ar0, ar1;
    short8_t abr;

    auto loadA = [&](int kt) {
        if constexpr (BF16) {
            abr = *reinterpret_cast<const short8_t*>(
                (const ushort_t*)A + ((size_t)(b * NN + n0 + br_)) * NN + kt * 64 + bc_);
        } else {
            const float* ap = (const float*)A;
            ar0 = *reinterpret_cast<const float4*>(ap + ((size_t)(b * NN + n0 + er0)) * NN + kt * 64 + ec0);
            ar1 = *reinterpret_cast<const float4*>(ap + ((size_t)(b * NN + n0 + er0 + 16)) * NN + kt * 64 + ec0);
        }
    };
    auto writeA = [&]() {
        if constexpr (BF16) {
            *reinterpret_cast<short8_t*>(&As_h[br_][bc_]) = abr;
        } else {
            ushort4 h4, l4;
            split2(ar0.x, h4.x, l4.x); split2(ar0.y, h4.y, l4.y);
            split2(ar0.z, h4.z, l4.z); split2(ar0.w, h4.w, l4.w);
            *reinterpret_cast<ushort4*>(&As_h[er0][ec0]) = h4;
            *reinterpret_cast<ushort4*>(&As_l[er0][ec0]) = l4;
            split2(ar1.x, h4.x, l4.x); split2(ar1.y, h4.y, l4.y);
            split2(ar1.z, h4.z, l4.z); split2(ar1.w, h4.w, l4.w);
            *reinterpret_cast<ushort4*>(&As_h[er0 + 16][ec0]) = h4;
            *reinterpret_cast<ushort4*>(&As_l[er0 + 16][ec0]) = l4;
        }
    };

    loadA(0);
    for (int kt = 0; kt < 32; ++kt) {
        writeA();
        __syncthreads();
        if (kt + 1 < 32) loadA(kt + 1);
#pragma unroll
        for (int kh = 0; kh < 2; ++kh) {
            short8_t ah = *reinterpret_cast<const short8_t*>(&As_h[wr + lr][kh * 32 + 8 * hq]);
            short8_t al;
            if constexpr (!BF16) al = *reinterpret_cast<const short8_t*>(&As_l[wr + lr][kh * 32 + 8 * hq]);
            const size_t pb = ((size_t)(b * 64 + kt * 2 + kh) * 8 + wc4) * 512 + (size_t)lane * 8;
            short8_t bh[4], bl[4];
#pragma unroll
            for (int t = 0; t < 4; ++t)
                bh[t] = *reinterpret_cast<const short8_t*>(mThp + pb + t * 512);
            if constexpr (!BF16 && SPLIT) {
#pragma unroll
                for (int t = 0; t < 4; ++t)
                    bl[t] = *reinterpret_cast<const short8_t*>(mTlp + pb + t * 512);
            }
#pragma unroll
            for (int t = 0; t < 4; ++t) {
                acc[t] = mfma16(ah, bh[t], acc[t]);
                if constexpr (!BF16) {
                    acc[t] = mfma16(al, bh[t], acc[t]);
                    if constexpr (SPLIT) acc[t] = mfma16(ah, bl[t], acc[t]);
                }
            }
        }
        __syncthreads();
    }

    // packed store into out rows (C/D: col=lane&15, row=(lane>>4)*4+q)
    char* ob = (char*)out;
    const int wc = wc4 * 16;
#pragma unroll
    for (int t = 0; t < 4; ++t)
#pragma unroll
        for (int q = 0; q < 4; ++q) {
            int row = wr + hq * 4 + q, col = wc + t * 16 + lr;
            size_t gr = (size_t)(b * NN + n0 + row);
            float v = fmaxf(acc[t][q], 0.f);
            if constexpr (BF16) {
                *(ushort_t*)(ob + gr * 256 + col * 2) = bf_rn(v);
            } else {
                ushort_t hi, lo;
                split2(v, hi, lo);
                *(ushort_t*)(ob + gr * 512 + col * 2) = hi;
                *(ushort_t*)(ob + gr * 512 + 256 + col * 2) = lo;
            }
        }
}

template<bool SPLIT>
__global__ __launch_bounds__(256) void msg_kernel(
    const int* __restrict__ flag, const void* __restrict__ A,
    const char* __restrict__ ws, void* __restrict__ out)
{
    __shared__ __align__(16) char smem[9216];
    if (*flag) msg_body<true, false>(smem, A, (const char*)ws, out);
    else       msg_body<false, SPLIT>(smem, A, (const char*)ws, out);
}

// ---------------------------------------------------------------------------
// GRU via MFMA, weights from packed frag-linear (contiguous 1KB B-loads).
// ---------------------------------------------------------------------------
template<bool BF16>
__device__ void gru_body(char* smem, const void* h, const char* ws, void* out)
{
    ushort_t (*msgh)[264] = (ushort_t(*)[264])smem;               // 16896
    ushort_t (*msgl)[264] = (ushort_t(*)[264])(smem + 16896);
    float    (*hf)[132]   = (float(*)[132])(smem + 33792);

    const ushort_t* wihh = (const ushort_t*)(ws + WS_WIHH);
    const ushort_t* wihl = (const ushort_t*)(ws + WS_WIHL);
    const ushort_t* whhh = (const ushort_t*)(ws + WS_WHHH);
    const ushort_t* whhl = (const ushort_t*)(ws + WS_WHHL);
    const float* bihf = (const float*)(ws + WS_BIH);
    const float* bhhf = (const float*)(ws + WS_BHH);

    const int tid = threadIdx.x;
    const int row0 = blockIdx.x * 32;
    char* ob = (char*)out;

    // stage packed msg (from out rows)
    if constexpr (BF16) {
#pragma unroll
        for (int j = 0; j < 2; ++j) {
            int e = j * 256 + tid;
            int r = e >> 4, c8 = (e & 15) * 8;
            short8_t v = *reinterpret_cast<const short8_t*>(ob + (size_t)(row0 + r) * 256 + c8 * 2);
            *(short8_t*)&msgh[r][c8] = v;
        }
    } else {
#pragma unroll
        for (int j = 0; j < 4; ++j) {
            int e = j * 256 + tid;
            int r = e >> 5, off = (e & 31) * 16;
            short8_t v = *reinterpret_cast<const short8_t*>(ob + (size_t)(row0 + r) * 512 + off);
            if (off < 256) *(short8_t*)&msgh[r][off >> 1] = v;
            else           *(short8_t*)&msgl[r][(off - 256) >> 1] = v;
        }
    }
    // stage h rows as fp32
    if constexpr (BF16) {
#pragma unroll
        for (int j = 0; j < 2; ++j) {
            int e = j * 256 + tid;
            int r = e >> 4, c8 = (e & 15) * 8;
            short8_t v = *reinterpret_cast<const short8_t*>((const ushort_t*)h + (size_t)(row0 + r) * HH + c8);
#pragma unroll
            for (int q = 0; q < 8; ++q) hf[r][c8 + q] = bfs_to_f(v[q]);
        }
    } else {
#pragma unroll
        for (int j = 0; j < 4; ++j) {
            int e = j * 256 + tid;
            int r = e >> 5, c4 = (e & 31) * 4;
            *(float4*)&hf[r][c4] = *reinterpret_cast<const float4*>((const float*)h + (size_t)(row0 + r) * HH + c4);
        }
    }
    __syncthreads();

    const int lane = tid & 63, wv = tid >> 6;
    const int lr = lane & 15, hq = lane >> 4;
    const int cw0 = wv * 32;

    f32x4_t accx[2][3][2], acch[2][3][2];
#pragma unroll
    for (int rt = 0; rt < 2; ++rt)
#pragma unroll
        for (int g = 0; g < 3; ++g)
#pragma unroll
            for (int ct = 0; ct < 2; ++ct) {
                accx[rt][g][ct][0] = 0.f; accx[rt][g][ct][1] = 0.f;
                accx[rt][g][ct][2] = 0.f; accx[rt][g][ct][3] = 0.f;
                acch[rt][g][ct][0] = 0.f; acch[rt][g][ct][1] = 0.f;
                acch[rt][g][ct][2] = 0.f; acch[rt][g][ct][3] = 0.f;
            }

    for (int k0 = 0; k0 < HH; k0 += 32) {
        short8_t amh[2], aml[2], ahh[2], ahl[2];
#pragma unroll
        for (int rt = 0; rt < 2; ++rt) {
            amh[rt] = *reinterpret_cast<const short8_t*>(&msgh[rt * 16 + lr][k0 + 8 * hq]);
            if constexpr (!BF16)
                aml[rt] = *reinterpret_cast<const short8_t*>(&msgl[rt * 16 + lr][k0 + 8 * hq]);
            float4 f0 = *(const float4*)&hf[rt * 16 + lr][k0 + 8 * hq];
            float4 f1 = *(const float4*)&hf[rt * 16 + lr][k0 + 8 * hq + 4];
#pragma unroll
            for (int j = 0; j < 4; ++j) {
                ushort_t hi, lo;
                split2(f4c(f0, j), hi, lo); ahh[rt][j] = (short)hi; ahl[rt][j] = (short)lo;
                split2(f4c(f1, j), hi, lo); ahh[rt][j + 4] = (short)hi; ahl[rt][j + 4] = (short)lo;
            }
        }
        const int ks = k0 >> 5;
#pragma unroll
        for (int g = 0; g < 3; ++g)
#pragma unroll
            for (int ct = 0; ct < 2; ++ct) {
                const size_t po = ((size_t)(ks * 24 + g * 8 + wv * 2 + ct)) * 512 + (size_t)lane * 8;
                short8_t bxh  = *reinterpret_cast<const short8_t*>(wihh + po);
                short8_t bhh2 = *reinterpret_cast<const short8_t*>(whhh + po);
                short8_t bxl, bhl2;
                if constexpr (!BF16) {
                    bxl  = *reinterpret_cast<const short8_t*>(wihl + po);
                    bhl2 = *reinterpret_cast<const short8_t*>(whhl + po);
                }
#pragma unroll
                for (int rt = 0; rt < 2; ++rt) {
                    accx[rt][g][ct] = mfma16(amh[rt], bxh, accx[rt][g][ct]);
                    acch[rt][g][ct] = mfma16(ahh[rt], bhh2, acch[rt][g][ct]);
                    if constexpr (!BF16) {
                        accx[rt][g][ct] = mfma16(aml[rt], bxh, accx[rt][g][ct]);
                        accx[rt][g][ct] = mfma16(amh[rt], bxl, accx[rt][g][ct]);
                        acch[rt][g][ct] = mfma16(ahl[rt], bhh2, acch[rt][g][ct]);
                        acch[rt][g][ct] = mfma16(ahh[rt], bhl2, acch[rt][g][ct]);
                    }
                }
            }
    }

    // combine + store
#pragma unroll
    for (int rt = 0; rt < 2; ++rt)
#pragma unroll
        for (int ct = 0; ct < 2; ++ct) {
            int col = cw0 + ct * 16 + lr;
            float brx = bihf[col],       brh = bhhf[col];
            float bzx = bihf[128 + col], bzh = bhhf[128 + col];
            float bnx = bihf[256 + col], bnh = bhhf[256 + col];
#pragma unroll
            for (int q = 0; q < 4; ++q) {
                int row = rt * 16 + hq * 4 + q;
                float gr_ = (accx[rt][0][ct][q] + brx) + (acch[rt][0][ct][q] + brh);
                float gz_ = (accx[rt][1][ct][q] + bzx) + (acch[rt][1][ct][q] + bzh);
                float gxn = accx[rt][2][ct][q] + bnx;
                float ghn = acch[rt][2][ct][q] + bnh;
                float rr = 1.f / (1.f + expf(-gr_));
                float zz = 1.f / (1.f + expf(-gz_));
                float nv = tanhf(gxn + rr * ghn);
                float hv = hf[row][col];
                float res = (1.f - zz) * nv + zz * hv;
                size_t o = (size_t)(row0 + row) * HH + col;
                if constexpr (BF16) ((ushort_t*)out)[o] = bf_rn(res);
                else                ((float*)out)[o]    = res;
            }
        }
}

__global__ __launch_bounds__(256) __attribute__((amdgpu_waves_per_eu(1, 2)))
void gru_kernel(
    const int* __restrict__ flag, const void* __restrict__ h,
    const char* __restrict__ ws, void* __restrict__ out)
{
    __shared__ __align__(16) char smem[50688];
    if (*flag) gru_body<true >(smem, h, (const char*)ws, out);
    else       gru_body<false>(smem, h, (const char*)ws, out);
}

// ---------------------------------------------------------------------------
// diagnostic fill
// ---------------------------------------------------------------------------
__global__ void diag_kernel(float* __restrict__ out, float val, int nfill)
{
    int i = blockIdx.x * 256 + threadIdx.x;
    if (i < nfill) out[i] = val;
}

// ---------------------------------------------------------------------------
extern "C" void kernel_launch(void* const* d_in, const int* in_sizes, int n_in,
                              void* d_out, int out_size, void* d_ws, size_t ws_size,
                              hipStream_t stream)
{
    const int expected[10] = {BN * HH, BB * NN * NN, HH * HH, HH, HH * HH, HH,
                              3 * HH * HH, 3 * HH * HH, 3 * HH, 3 * HH};
    int bad = -1;
    if (n_in < 10) bad = 50;
    else {
        for (int i = 0; i < 10; ++i)
            if (in_sizes[i] != expected[i]) { bad = i; break; }
    }
    if (bad < 0 && out_size != BN * HH) bad = 60;
    if (bad >= 0) {
        float val = 10000.0f + 1000.0f * (float)bad;
        int nfill = out_size / 2;
        diag_kernel<<<(nfill + 255) / 256, 256, 0, stream>>>((float*)d_out, val, nfill);
        return;
    }

    const void* h   = d_in[0];
    const void* A   = d_in[1];
    const void* W1  = d_in[2];
    const void* b1  = d_in[3];
    const void* W2  = d_in[4];
    const void* b2  = d_in[5];
    const void* Wih = d_in[6];
    const void* Whh = d_in[7];
    const void* bih = d_in[8];
    const void* bhh = d_in[9];

    const size_t need_bf  = WS_M + (size_t)BN * HH * 2;    // packed mT hi only
    const size_t need_f32 = WS_M + (size_t)BN * HH * 4;    // + packed mT lo
    if (ws_size < need_bf) {
        float val = 2000.0f + (float)(ws_size >> 10);
        int nfill = out_size / 2;
        diag_kernel<<<(nfill + 255) / 256, 256, 0, stream>>>((float*)d_out, val, nfill);
        return;
    }
    const bool split = (ws_size >= need_f32);
    int*  flag = (int*)d_ws;
    char* ws   = (char*)d_ws;

    detect_kernel<<<1, 256, 0, stream>>>((const ushort_t*)A, flag);
    prep_kernel<<<64, 256, 0, stream>>>(flag, W1, b1, W2, b2, Wih, Whh, bih, bhh, ws);

    if (split) {
        mlp_kernel<true ><<<BN / 32, 256, 0, stream>>>(flag, h, ws);
        msg_kernel<true ><<<BB * (NN / 32), 256, 0, stream>>>(flag, A, ws, d_out);
    } else {
        mlp_kernel<false><<<BN / 32, 256, 0, stream>>>(flag, h, ws);
        msg_kernel<false><<<BB * (NN / 32), 256, 0, stream>>>(flag, A, ws, d_out);
    }
    gru_kernel<<<BN / 32, 256, 0, stream>>>(flag, h, ws, d_out);
}